// Round 5
// baseline (357.954 us; speedup 1.0000x reference)
//
#include <hip/hip_runtime.h>
#include <stdint.h>

typedef unsigned short u16;
typedef __bf16 bf16x8 __attribute__((ext_vector_type(8)));
typedef float f32x4 __attribute__((ext_vector_type(4)));
typedef unsigned short us8 __attribute__((ext_vector_type(8)));
typedef unsigned short us4 __attribute__((ext_vector_type(4)));

#define B_ 8
#define F_ 16
#define NS_ 196
#define J_ 24
#define H_ 8
#define N_ 3160
#define RTOK 25280   // B_*N_
#define SKEY 220     // J_+NS_
#define JSPLIT 13    // ceil(3160/256) key-splits for joint attention

union U8 { us8 u; bf16x8 b; };

static __device__ __forceinline__ float bf2f(u16 v){
  unsigned int u = ((unsigned int)v) << 16; float f; __builtin_memcpy(&f, &u, 4); return f;
}
static __device__ __forceinline__ u16 f2bf(float f){
  unsigned int u; __builtin_memcpy(&u, &f, 4);
  u = (u + 0x7fffu + ((u >> 16) & 1u)) >> 16; return (u16)u;
}
static __device__ __forceinline__ void g2l16(const u16* g, u16* l){
  __builtin_amdgcn_global_load_lds((const __attribute__((address_space(1))) void*)g,
                                   (__attribute__((address_space(3))) void*)l, 16, 0, 0);
}
// RoPE on 8 bf16 elems with fp32 sin/cos
static __device__ __forceinline__ us8 rope8(us8 t, const float* __restrict__ sv,
                                            const float* __restrict__ cv){
  us8 o;
  #pragma unroll
  for (int i = 0; i < 8; i += 2){
    float e0 = bf2f(t[i]), e1 = bf2f(t[i+1]);
    o[i]   = f2bf(e0 * cv[i]   - e1 * sv[i]);
    o[i+1] = f2bf(e1 * cv[i+1] + e0 * sv[i+1]);
  }
  return o;
}

// ---------------- fp32 -> bf16 convert (x) ----------------
__global__ __launch_bounds__(256) void cvt_bf16(const float* __restrict__ src, u16* __restrict__ dst, int n4){
  int i = blockIdx.x * 256 + threadIdx.x;
  if (i < n4){
    float4 v = ((const float4*)src)[i];
    us4 o; o[0] = f2bf(v.x); o[1] = f2bf(v.y); o[2] = f2bf(v.z); o[3] = f2bf(v.w);
    ((us4*)dst)[i] = o;
  }
}

// ---------------- transpose fp32 -> bf16 (B-operand K-contiguity) ----------------
__global__ __launch_bounds__(256) void ktranspose(const float* __restrict__ src, u16* __restrict__ dst,
                                                  int rows, int cols){
  __shared__ float t[32][33];
  int tx = threadIdx.x & 31, ty = threadIdx.x >> 5;
  int c0 = blockIdx.x * 32, r0 = blockIdx.y * 32;
  #pragma unroll
  for (int i = 0; i < 4; i++) t[ty + 8*i][tx] = src[(long)(r0 + ty + 8*i) * cols + c0 + tx];
  __syncthreads();
  #pragma unroll
  for (int i = 0; i < 4; i++) dst[(long)(c0 + ty + 8*i) * rows + r0 + tx] = f2bf(t[tx][ty + 8*i]);
}

// ---------------- GEMM core: C[128x128] tile, K=512, BK=32, bf16, B-DIRECT ----------------
// LDS-BW was the R4 wall (48KB/step ~ 529cy). Now only A goes through LDS (8KB write +
// 16KB read per step); B fragments load straight from L2-resident WT into registers via
// inline-asm global_load_dwordx4 (16 fully-used 64B lines per instr).
// Per-wave vmem FIFO per step (A=2 gload_lds ops, B=4 reg-load ops), interleaved
// [A(t),B(t),A(t+1),B(t+1),A(t+2),B(t+2)]: vmcnt(12) leaves A/B(t+1),A/B(t+2) in flight
// (2-step ~600-1000cy latency window); tail 12 -> 6 -> 0.
// A chunk-XOR swizzle via pre-swizzled global source (gload_lds dest linear, rule #21).
static __device__ __forceinline__ void stage_A(const u16* __restrict__ Ag, u16* At, int bm, int k0){
  const int tid = threadIdx.x, wave = tid >> 6, lane = tid & 63;
  #pragma unroll
  for (int j = 0; j < 2; j++){
    int ca = wave*128 + j*64 + lane;         // 16B-chunk id 0..511 (LDS dest = ca*16B, linear)
    int row = ca >> 2;
    int c8 = (((ca & 3) ^ ((ca >> 3) & 3)) * 8);   // pre-swizzled source column
    int ga = bm*128 + row; ga = ga < RTOK ? ga : RTOK - 1;   // clamp last tile
    g2l16(Ag + (long)ga*512 + k0 + c8, At + wave*1024 + j*512);
  }
}

#define LOADB4(dst, off) do{                                                     \
    asm volatile("global_load_dwordx4 %0, %1, off offset:%2"                     \
                 : "=v"((dst)[0].u) : "v"(bb0), "n"(off) : "memory");            \
    asm volatile("global_load_dwordx4 %0, %1, off offset:%2"                     \
                 : "=v"((dst)[1].u) : "v"(bb1), "n"(off) : "memory");            \
    asm volatile("global_load_dwordx4 %0, %1, off offset:%2"                     \
                 : "=v"((dst)[2].u) : "v"(bb2), "n"(off) : "memory");            \
    asm volatile("global_load_dwordx4 %0, %1, off offset:%2"                     \
                 : "=v"((dst)[3].u) : "v"(bb3), "n"(off) : "memory");            \
  }while(0)

static __device__ __forceinline__ void compute_bd(const u16* Ac, const U8 (&bfr)[4],
                                                  f32x4 (&acc)[4][4], int wave, int quad, int l15){
  const int r0 = (wave >> 1) * 64;
  const int pc = quad ^ ((l15 >> 1) & 3);    // physical chunk (row-dependent swizzle)
  bf16x8 af[4];
  #pragma unroll
  for (int mt = 0; mt < 4; mt++) af[mt] = *(const bf16x8*)(Ac + (r0 + mt*16 + l15)*32 + pc*8);
  #pragma unroll
  for (int mt = 0; mt < 4; mt++)
    #pragma unroll
    for (int nt = 0; nt < 4; nt++)
      acc[mt][nt] = __builtin_amdgcn_mfma_f32_16x16x32_bf16(af[mt], bfr[nt].b, acc[mt][nt], 0, 0, 0);
}

static __device__ __forceinline__ void gemm_core_bd(const u16* __restrict__ Ag, const u16* __restrict__ Bg,
                                                    u16* At, int bm, int bn, f32x4 (&acc)[4][4]){
  const int tid = threadIdx.x, wave = tid >> 6, lane = tid & 63, quad = lane >> 4, l15 = lane & 15;
  const int c0 = (wave & 1) * 64;
  const u16* bb0 = Bg + ((long)(bn*128 + c0 +  0 + l15))*512 + quad*8;
  const u16* bb1 = bb0 + 16*512;
  const u16* bb2 = bb0 + 32*512;
  const u16* bb3 = bb0 + 48*512;
  U8 bcur[4], bnxt[4], bn2[4];
  // prologue: interleave [A0, B0, A1, B1] in the vmem FIFO
  stage_A(Ag, At, bm, 0);
  LOADB4(bcur, 0);
  stage_A(Ag, At + 4096, bm, 32);
  LOADB4(bnxt, 64);
  #pragma unroll
  for (int t = 0; t < 16; ++t){
    if (t + 2 < 16){
      stage_A(Ag, At + ((t+2)&3)*4096, bm, (t+2)*32);
      switch (t){   // compile-time offset (t+2)*64 bytes for B(t+2)
        case 0:  LOADB4(bn2, 2*64);  break;
        case 1:  LOADB4(bn2, 3*64);  break;
        case 2:  LOADB4(bn2, 4*64);  break;
        case 3:  LOADB4(bn2, 5*64);  break;
        case 4:  LOADB4(bn2, 6*64);  break;
        case 5:  LOADB4(bn2, 7*64);  break;
        case 6:  LOADB4(bn2, 8*64);  break;
        case 7:  LOADB4(bn2, 9*64);  break;
        case 8:  LOADB4(bn2, 10*64); break;
        case 9:  LOADB4(bn2, 11*64); break;
        case 10: LOADB4(bn2, 12*64); break;
        case 11: LOADB4(bn2, 13*64); break;
        case 12: LOADB4(bn2, 14*64); break;
        default: LOADB4(bn2, 15*64); break;
      }
    }
    __builtin_amdgcn_sched_barrier(0);        // pin issues above the counted wait
    if (t < 14)       asm volatile("s_waitcnt vmcnt(12)" ::: "memory");  // A/B(t) landed; t+1,t+2 in flight
    else if (t == 14) asm volatile("s_waitcnt vmcnt(6)"  ::: "memory");
    else              asm volatile("s_waitcnt vmcnt(0)"  ::: "memory");
    __builtin_amdgcn_sched_barrier(0);        // nothing hoists above the wait
    __builtin_amdgcn_s_barrier();             // raw barrier: NO vmcnt(0) drain
    __builtin_amdgcn_sched_barrier(0);        // ds_reads stay below the barrier
    compute_bd(At + (t&3)*4096, bcur, acc, wave, quad, l15);
    #pragma unroll
    for (int nt = 0; nt < 4; nt++){ bcur[nt] = bnxt[nt]; bnxt[nt] = bn2[nt]; }
  }
}

// ---------------- QKV GEMM: xb @ wqkv^T, scatter to q/k/v [bh][n][64] bf16, q*0.125 ----------------
// Flat grid 2376 with XCD-chunked mapping: all 12 bn-tiles of one bm run consecutively on
// the same XCD -> the X row-panel stays L2-resident across bn.
__global__ __launch_bounds__(256) void gemm_qkv(const u16* __restrict__ X, const u16* __restrict__ WT,
                                                u16* __restrict__ qb, u16* __restrict__ kb, u16* __restrict__ vb){
  __shared__ __attribute__((aligned(16))) u16 At[4*128*32];
  const int tid = threadIdx.x, wave = tid >> 6, quad = (tid & 63) >> 4, l15 = tid & 15;
  const int id = blockIdx.x;
  const int logical = (id & 7) * 297 + (id >> 3);   // 2376/8 = 297, bijective
  const int bm = logical / 12, bn = logical % 12;
  f32x4 acc[4][4] = {};
  gemm_core_bd(X, WT, At, bm, bn, acc);
  const int rbase = bm*128 + (wave >> 1)*64;
  const int cbase = bn*128 + (wave & 1)*64;
  // cbase is a multiple of 64 -> target tensor t and head index are wave-uniform
  const int t = cbase >> 9;
  const int head = (cbase & 511) >> 6;
  u16* __restrict__ dst = (t == 0) ? qb : ((t == 1) ? kb : vb);
  const float scl = (t == 0) ? 0.125f : 1.0f;
  #pragma unroll
  for (int mt = 0; mt < 4; mt++)
  #pragma unroll
  for (int r = 0; r < 4; r++){
    int row = rbase + mt*16 + quad*4 + r;
    if (row < RTOK){
      int b = row / N_, n = row - b * N_;
      long base = ((long)(b*8 + head) * N_ + n) * 64;
      #pragma unroll
      for (int nt = 0; nt < 4; nt++)
        dst[base + nt*16 + l15] = f2bf(acc[mt][nt][r] * scl);
    }
  }
}

// ---------------- OUT GEMM: aob @ wout^T + b_out -> d_out (fp32) ----------------
__global__ __launch_bounds__(256) void gemm_out(const u16* __restrict__ A, const u16* __restrict__ WT,
                                                const float* __restrict__ bias, float* __restrict__ out){
  __shared__ __attribute__((aligned(16))) u16 At[4*128*32];
  const int tid = threadIdx.x, wave = tid >> 6, quad = (tid & 63) >> 4, l15 = tid & 15;
  const int id = blockIdx.x;
  const int logical = (id & 7) * 99 + (id >> 3);    // 792/8 = 99, bijective
  const int bm = logical >> 2, bn = logical & 3;
  f32x4 acc[4][4] = {};
  gemm_core_bd(A, WT, At, bm, bn, acc);
  const int rbase = bm*128 + (wave >> 1)*64;
  const int cbase = bn*128 + (wave & 1)*64;
  #pragma unroll
  for (int mt = 0; mt < 4; mt++)
  #pragma unroll
  for (int nt = 0; nt < 4; nt++)
  #pragma unroll
  for (int r = 0; r < 4; r++){
    int row = rbase + mt*16 + quad*4 + r;
    if (row < RTOK){
      int col = cbase + nt*16 + l15;
      out[(long)row*512 + col] = acc[mt][nt][r] + bias[col];
    }
  }
}

// ---------------- joint attention, key-split partials: grid (64, JSPLIT) ----------------
__global__ __launch_bounds__(256) void joint_part(const u16* __restrict__ qb, const u16* __restrict__ kb,
                                                  const u16* __restrict__ vb, float* __restrict__ po,
                                                  float* __restrict__ pm, float* __restrict__ pl){
  __shared__ __attribute__((aligned(16))) u16 Qj[32*64];
  __shared__ __attribute__((aligned(16))) u16 Kc[128*64];
  __shared__ __attribute__((aligned(16))) u16 Vt[64*128];
  __shared__ __attribute__((aligned(16))) u16 Pl[32*128];
  __shared__ float redm[4][32];
  __shared__ float redl[4][32];
  __shared__ float mrow[32], lrow[32], arow[32];
  __shared__ float Oacc[32*64];
  const int tid = threadIdx.x, wave = tid >> 6, lane = tid & 63, quad = lane >> 4, l15 = lane & 15;
  const int bh = blockIdx.x, split = blockIdx.y;
  const int kbeg = split * 256;
  const int kend = (kbeg + 256 < N_) ? kbeg + 256 : N_;
  const u16* kbh = kb + (long)bh * N_ * 64;
  const u16* vbh = vb + (long)bh * N_ * 64;
  const u16* qbh = qb + (long)bh * N_ * 64;
  { // stage Qj (rows 24..31 zero)
    int row = tid >> 3, c8 = (tid & 7) * 8;
    us8 z;
    #pragma unroll
    for (int i = 0; i < 8; i++) z[i] = 0;
    *(us8*)(Qj + row*64 + c8) = (row < J_) ? *(const us8*)(qbh + row*64 + c8) : z;
  }
  if (tid < 32){ mrow[tid] = -1e30f; lrow[tid] = 0.f; }
  f32x4 o[2][4] = {};
  __syncthreads();
  for (int c0 = kbeg; c0 < kend; c0 += 128){
    // stage K chunk + V^T chunk (clamped rows; masked later)
    #pragma unroll
    for (int it = 0; it < 4; ++it){
      int j = tid + it*256;
      int row = j >> 3, c8 = (j & 7) * 8;
      int gr = c0 + row; gr = gr < N_ ? gr : N_ - 1;
      *(us8*)(Kc + row*64 + c8) = *(const us8*)(kbh + (long)gr*64 + c8);
      us8 vv = *(const us8*)(vbh + (long)gr*64 + c8);
      #pragma unroll
      for (int i = 0; i < 8; i++) Vt[(c8 + i)*128 + row] = vv[i];
    }
    __syncthreads();
    // QK^T for this wave's 32 keys
    f32x4 sim[2][2];
    #pragma unroll
    for (int mt = 0; mt < 2; mt++){
      bf16x8 a0 = *(const bf16x8*)(Qj + (mt*16 + l15)*64 + quad*8);
      bf16x8 a1 = *(const bf16x8*)(Qj + (mt*16 + l15)*64 + 32 + quad*8);
      #pragma unroll
      for (int ntl = 0; ntl < 2; ntl++){
        int krow = wave*32 + ntl*16 + l15;
        bf16x8 b0 = *(const bf16x8*)(Kc + krow*64 + quad*8);
        bf16x8 b1 = *(const bf16x8*)(Kc + krow*64 + 32 + quad*8);
        f32x4 s = {0.f, 0.f, 0.f, 0.f};
        s = __builtin_amdgcn_mfma_f32_16x16x32_bf16(a0, b0, s, 0, 0, 0);
        s = __builtin_amdgcn_mfma_f32_16x16x32_bf16(a1, b1, s, 0, 0, 0);
        if (c0 + krow >= N_){
          #pragma unroll
          for (int r = 0; r < 4; r++) s[r] = -1e30f;
        }
        sim[mt][ntl] = s;
      }
    }
    // per-row partial max (over this wave's keys)
    #pragma unroll
    for (int mt = 0; mt < 2; mt++)
    #pragma unroll
    for (int r = 0; r < 4; r++){
      float m = fmaxf(sim[mt][0][r], sim[mt][1][r]);
      #pragma unroll
      for (int sh = 1; sh < 16; sh <<= 1) m = fmaxf(m, __shfl_xor(m, sh, 64));
      if (l15 == 0) redm[wave][mt*16 + quad*4 + r] = m;
    }
    __syncthreads();
    if (tid < 32){
      float cm = fmaxf(fmaxf(redm[0][tid], redm[1][tid]), fmaxf(redm[2][tid], redm[3][tid]));
      float nm = fmaxf(mrow[tid], cm);
      arow[tid] = __expf(mrow[tid] - nm);
      mrow[tid] = nm;
    }
    __syncthreads();
    // p = exp(sim - m), write P, partial sums, rescale O
    #pragma unroll
    for (int mt = 0; mt < 2; mt++)
    #pragma unroll
    for (int r = 0; r < 4; r++){
      int rowi = mt*16 + quad*4 + r;
      float nm = mrow[rowi];
      float p0 = __expf(sim[mt][0][r] - nm);
      float p1 = __expf(sim[mt][1][r] - nm);
      float s = p0 + p1;
      #pragma unroll
      for (int sh = 1; sh < 16; sh <<= 1) s += __shfl_xor(s, sh, 64);
      if (l15 == 0) redl[wave][rowi] = s;
      Pl[rowi*128 + wave*32 + l15]      = f2bf(p0);
      Pl[rowi*128 + wave*32 + 16 + l15] = f2bf(p1);
      float al = arow[rowi];
      #pragma unroll
      for (int ntd = 0; ntd < 4; ntd++) o[mt][ntd][r] *= al;
    }
    __syncthreads();
    if (tid < 32)
      lrow[tid] = lrow[tid]*arow[tid] + redl[0][tid] + redl[1][tid] + redl[2][tid] + redl[3][tid];
    // PV: this wave's 32 keys
    #pragma unroll
    for (int mt = 0; mt < 2; mt++){
      bf16x8 ap = *(const bf16x8*)(Pl + (mt*16 + l15)*128 + wave*32 + quad*8);
      #pragma unroll
      for (int ntd = 0; ntd < 4; ntd++){
        bf16x8 bv = *(const bf16x8*)(Vt + (ntd*16 + l15)*128 + wave*32 + quad*8);
        o[mt][ntd] = __builtin_amdgcn_mfma_f32_16x16x32_bf16(ap, bv, o[mt][ntd], 0, 0, 0);
      }
    }
    __syncthreads();
  }
  // merge wave partials
  #pragma unroll 1
  for (int w = 0; w < 4; ++w){
    if (wave == w){
      #pragma unroll
      for (int mt = 0; mt < 2; mt++)
      #pragma unroll
      for (int ntd = 0; ntd < 4; ntd++)
      #pragma unroll
      for (int r = 0; r < 4; r++){
        int rowi = mt*16 + quad*4 + r, d = ntd*16 + l15;
        if (w == 0) Oacc[rowi*64 + d]  = o[mt][ntd][r];
        else        Oacc[rowi*64 + d] += o[mt][ntd][r];
      }
    }
    __syncthreads();
  }
  const long pbase = (long)(bh*JSPLIT + split) * J_;
  for (int j = tid; j < J_*64; j += 256){
    int row = j >> 6, d = j & 63;
    po[(pbase + row)*64 + d] = Oacc[j];
  }
  if (tid < J_){ pm[pbase + tid] = mrow[tid]; pl[pbase + tid] = lrow[tid]; }
}

// ---------------- joint merge: combine JSPLIT partials per bh ----------------
__global__ __launch_bounds__(256) void joint_merge(const float* __restrict__ po, const float* __restrict__ pm,
                                                   const float* __restrict__ pl, u16* __restrict__ ao){
  __shared__ float sc[JSPLIT][J_];
  __shared__ float lg[J_];
  const int tid = threadIdx.x, bh = blockIdx.x;
  if (tid < J_){
    float m = -1e30f;
    #pragma unroll
    for (int s = 0; s < JSPLIT; s++) m = fmaxf(m, pm[(bh*JSPLIT + s)*J_ + tid]);
    float l = 0.f;
    #pragma unroll
    for (int s = 0; s < JSPLIT; s++){
      float e = __expf(pm[(bh*JSPLIT + s)*J_ + tid] - m);
      sc[s][tid] = e;
      l += pl[(bh*JSPLIT + s)*J_ + tid] * e;
    }
    lg[tid] = l;
  }
  __syncthreads();
  const int b = bh >> 3, h = bh & 7;
  for (int j = tid; j < J_*64; j += 256){
    int row = j >> 6, d = j & 63;
    float acc = 0.f;
    #pragma unroll
    for (int s = 0; s < JSPLIT; s++)
      acc += po[((long)(bh*JSPLIT + s)*J_ + row)*64 + d] * sc[s][row];
    ao[((long)(b*N_ + row))*512 + h*64 + d] = f2bf(acc / lg[row]);
  }
}

// ---------------- spatial attention: per (bh,f), 196 q vs 220 keys, RoPE fused ----------------
__global__ __launch_bounds__(256, 2) void spatial_attn(const u16* __restrict__ qb, const u16* __restrict__ kb,
                                                    const u16* __restrict__ vb, const float* __restrict__ sinb,
                                                    const float* __restrict__ cosb, u16* __restrict__ ao){
  __shared__ __attribute__((aligned(16))) u16 Kl[224*64];
  __shared__ __attribute__((aligned(16))) u16 Vt[64*256];
  __shared__ __attribute__((aligned(16))) u16 Pl[4*16*32];
  const int tid = threadIdx.x, wave = tid >> 6, lane = tid & 63, quad = lane >> 4, l15 = lane & 15;
  const int bh = blockIdx.x >> 4, f = blockIdx.x & 15;
  const u16* kbh = kb + (long)bh * N_ * 64;
  const u16* vbh = vb + (long)bh * N_ * 64;
  const u16* qbh = qb + (long)bh * N_ * 64 + (long)(J_ + f*NS_) * 64;
  // stage K rows 0..223, swizzled (rows 24..219 get RoPE on dims<32; rows 220..223 zeroed)
  for (int j = tid; j < 224*8; j += 256){
    int n = j >> 3, c8 = (j & 7) * 8;
    us8 kv;
    if (n < SKEY){
      kv = *(const us8*)(kbh + (long)((n < J_) ? n : n + f*NS_) * 64 + c8);
      if (n >= J_ && c8 < 32){
        int ns = n - J_;
        kv = rope8(kv, sinb + ns*32 + c8, cosb + ns*32 + c8);
      }
    } else {
      #pragma unroll
      for (int i = 0; i < 8; i++) kv[i] = 0;
    }
    *(us8*)((char*)Kl + (((n << 7) + c8*2) ^ ((n & 7) << 4))) = kv;
  }
  // stage V^T swizzled: thread t owns key-column n = t (wave spans 64 consecutive cols -> 2-way banks)
  if (tid < 224){
    const int n = tid;
    const bool valid = n < SKEY;
    const u16* src = vbh + (long)((n < J_) ? n : n + f*NS_) * 64;
    #pragma unroll
    for (int d0 = 0; d0 < 64; d0 += 8){
      us8 vv;
      if (valid) vv = *(const us8*)(src + d0);
      else {
        #pragma unroll
        for (int i = 0; i < 8; i++) vv[i] = 0;
      }
      #pragma unroll
      for (int i = 0; i < 8; i++){
        int d = d0 + i;
        *(u16*)((char*)Vt + (((d << 9) + n*2) ^ ((d & 7) << 4))) = vv[i];
      }
    }
  }
  __syncthreads();
  const int b = bh >> 3, h = bh & 7;
  #pragma unroll 1
  for (int mt = 0; mt < 4; ++mt){
    int qrow = wave*64 + mt*16 + l15;
    int qi = qrow < NS_ ? qrow : NS_ - 1;           // clamp padded rows (stores guarded)
    U8 a0u, a1u;
    a0u.u = *(const us8*)(qbh + (long)qi*64 + quad*8);
    a0u.u = rope8(a0u.u, sinb + qi*32 + quad*8, cosb + qi*32 + quad*8);
    a1u.u = *(const us8*)(qbh + (long)qi*64 + 32 + quad*8);
    f32x4 sim[14];
    #pragma unroll
    for (int nt = 0; nt < 14; ++nt){
      int krow = nt*16 + l15;
      bf16x8 b0 = *(const bf16x8*)((const char*)Kl + (((krow << 7) + quad*16)      ^ ((krow & 7) << 4)));
      bf16x8 b1 = *(const bf16x8*)((const char*)Kl + (((krow << 7) + 64 + quad*16) ^ ((krow & 7) << 4)));
      f32x4 s = {0.f, 0.f, 0.f, 0.f};
      s = __builtin_amdgcn_mfma_f32_16x16x32_bf16(a0u.b, b0, s, 0, 0, 0);
      s = __builtin_amdgcn_mfma_f32_16x16x32_bf16(a1u.b, b1, s, 0, 0, 0);
      sim[nt] = s;
    }
    if (l15 >= 12){  // keys 220..223 are padding
      #pragma unroll
      for (int r = 0; r < 4; r++) sim[13][r] = -1e30f;
    }
    // full softmax in registers (rows live in quads; reduce over 16 lanes)
    #pragma unroll
    for (int r = 0; r < 4; r++){
      float m = sim[0][r];
      #pragma unroll
      for (int nt = 1; nt < 14; nt++) m = fmaxf(m, sim[nt][r]);
      #pragma unroll
      for (int sh = 1; sh < 16; sh <<= 1) m = fmaxf(m, __shfl_xor(m, sh, 64));
      float s = 0.f;
      #pragma unroll
      for (int nt = 0; nt < 14; nt++){ float p = __expf(sim[nt][r] - m); sim[nt][r] = p; s += p; }
      #pragma unroll
      for (int sh = 1; sh < 16; sh <<= 1) s += __shfl_xor(s, sh, 64);
      float inv = 1.f / s;
      #pragma unroll
      for (int nt = 0; nt < 14; nt++) sim[nt][r] *= inv;
    }
    // PV in 7 chunks of 32 keys; P round-trip through per-wave LDS (no block barrier needed).
    f32x4 o[4] = {};
    u16* pw = Pl + wave*512;
    #pragma unroll
    for (int c = 0; c < 7; c++){
      #pragma unroll
      for (int h2 = 0; h2 < 2; h2++){
        #pragma unroll
        for (int r = 0; r < 4; r++)
          pw[(quad*4 + r)*32 + h2*16 + l15] = f2bf(sim[2*c + h2][r]);
      }
      __builtin_amdgcn_wave_barrier();
      bf16x8 ap = *(const bf16x8*)(pw + l15*32 + quad*8);
      #pragma unroll
      for (int ntd = 0; ntd < 4; ntd++){
        int vrow = ntd*16 + l15;
        bf16x8 bv = *(const bf16x8*)((const char*)Vt + (((vrow << 9) + c*64 + quad*16) ^ ((vrow & 7) << 4)));
        o[ntd] = __builtin_amdgcn_mfma_f32_16x16x32_bf16(ap, bv, o[ntd], 0, 0, 0);
      }
      __builtin_amdgcn_wave_barrier();
    }
    #pragma unroll
    for (int ntd = 0; ntd < 4; ntd++)
    #pragma unroll
    for (int r = 0; r < 4; r++){
      int qr = wave*64 + mt*16 + quad*4 + r;
      if (qr < NS_){
        int n = J_ + f*NS_ + qr;
        ao[((long)(b*N_ + n))*512 + h*64 + ntd*16 + l15] = f2bf(o[ntd][r]);
      }
    }
  }
}

extern "C" void kernel_launch(void* const* d_in, const int* in_sizes, int n_in,
                              void* d_out, int out_size, void* d_ws, size_t ws_size,
                              hipStream_t stream){
  (void)in_sizes; (void)n_in; (void)out_size; (void)ws_size;
  const float* x    = (const float*)d_in[0];
  const float* wqkv = (const float*)d_in[1];
  const float* wout = (const float*)d_in[2];
  const float* bout = (const float*)d_in[3];
  const float* sinb = (const float*)d_in[4];
  const float* cosb = (const float*)d_in[5];
  float* out = (float*)d_out;
  u16* ws  = (u16*)d_ws;
  u16* qb  = ws;                       // [64][3160][64] bf16
  u16* kb  = qb  + 12943360;
  u16* vb  = kb  + 12943360;
  u16* xb  = vb  + 12943360;           // x bf16 [25280][512]; later reused as aob [B][N][512]
  u16* aob = xb;                       //   (alias: xb dead after gemm_qkv)
  u16* wt1 = xb  + 12943360;           // w_qkv^T bf16 [1536][512]
  u16* wt2 = wt1 + 786432;             // w_out^T bf16 [512][512]
  float* po = (float*)(wt2 + 262144);  // [64][JSPLIT][24][64] fp32 partial O
  float* pm = po + 64*JSPLIT*J_*64;    // [64][JSPLIT][24]
  float* pl = pm + 64*JSPLIT*J_;
  cvt_bf16<<<dim3((12943360/4 + 255)/256), 256, 0, stream>>>(x, xb, 12943360/4);
  ktranspose<<<dim3(48, 16), 256, 0, stream>>>(wqkv, wt1, 512, 1536);
  ktranspose<<<dim3(16, 16), 256, 0, stream>>>(wout, wt2, 512, 512);
  gemm_qkv<<<dim3(2376), 256, 0, stream>>>(xb, wt1, qb, kb, vb);
  joint_part<<<dim3(64, JSPLIT), 256, 0, stream>>>(qb, kb, vb, po, pm, pl);
  joint_merge<<<dim3(64), 256, 0, stream>>>(po, pm, pl, aob);
  spatial_attn<<<dim3(1024), 256, 0, stream>>>(qb, kb, vb, sinb, cosb, aob);
  gemm_out<<<dim3(792), 256, 0, stream>>>(aob, wt2, bout, out);
}

// Round 6
// 303.529 us; speedup vs baseline: 1.1793x; 1.1793x over previous
//
#include <hip/hip_runtime.h>
#include <stdint.h>

typedef unsigned short u16;
typedef __bf16 bf16x8 __attribute__((ext_vector_type(8)));
typedef float f32x4 __attribute__((ext_vector_type(4)));
typedef unsigned short us8 __attribute__((ext_vector_type(8)));
typedef unsigned short us4 __attribute__((ext_vector_type(4)));

#define B_ 8
#define F_ 16
#define NS_ 196
#define J_ 24
#define H_ 8
#define N_ 3160
#define RTOK 25280   // B_*N_
#define SKEY 220     // J_+NS_
#define JSPLIT 13    // ceil(3160/256) key-splits for joint attention

union U8 { us8 u; bf16x8 b; };

static __device__ __forceinline__ float bf2f(u16 v){
  unsigned int u = ((unsigned int)v) << 16; float f; __builtin_memcpy(&f, &u, 4); return f;
}
static __device__ __forceinline__ u16 f2bf(float f){
  unsigned int u; __builtin_memcpy(&u, &f, 4);
  u = (u + 0x7fffu + ((u >> 16) & 1u)) >> 16; return (u16)u;
}
static __device__ __forceinline__ void g2l16(const u16* g, u16* l){
  __builtin_amdgcn_global_load_lds((const __attribute__((address_space(1))) void*)g,
                                   (__attribute__((address_space(3))) void*)l, 16, 0, 0);
}
// RoPE on 8 bf16 elems with fp32 sin/cos
static __device__ __forceinline__ us8 rope8(us8 t, const float* __restrict__ sv,
                                            const float* __restrict__ cv){
  us8 o;
  #pragma unroll
  for (int i = 0; i < 8; i += 2){
    float e0 = bf2f(t[i]), e1 = bf2f(t[i+1]);
    o[i]   = f2bf(e0 * cv[i]   - e1 * sv[i]);
    o[i+1] = f2bf(e1 * cv[i+1] + e0 * sv[i+1]);
  }
  return o;
}

// ---------------- fp32 -> bf16 convert (x) ----------------
__global__ __launch_bounds__(256) void cvt_bf16(const float* __restrict__ src, u16* __restrict__ dst, int n4){
  int i = blockIdx.x * 256 + threadIdx.x;
  if (i < n4){
    float4 v = ((const float4*)src)[i];
    us4 o; o[0] = f2bf(v.x); o[1] = f2bf(v.y); o[2] = f2bf(v.z); o[3] = f2bf(v.w);
    ((us4*)dst)[i] = o;
  }
}

// ---------------- transpose fp32 -> bf16, both weights in ONE launch ----------------
// grid (64,16): bx<48 -> wqkv(512x1536)->wt1 ; bx>=48 -> wout(512x512)->wt2
__global__ __launch_bounds__(256) void ktranspose2(const float* __restrict__ s1, u16* __restrict__ d1,
                                                   const float* __restrict__ s2, u16* __restrict__ d2){
  __shared__ float t[32][33];
  const int bx = blockIdx.x;
  const float* src; u16* dst; int cols; int c0;
  if (bx < 48){ src = s1; dst = d1; cols = 1536; c0 = bx*32; }
  else        { src = s2; dst = d2; cols = 512;  c0 = (bx-48)*32; }
  const int rows = 512;
  int tx = threadIdx.x & 31, ty = threadIdx.x >> 5;
  int r0 = blockIdx.y * 32;
  #pragma unroll
  for (int i = 0; i < 4; i++) t[ty + 8*i][tx] = src[(long)(r0 + ty + 8*i) * cols + c0 + tx];
  __syncthreads();
  #pragma unroll
  for (int i = 0; i < 4; i++) dst[(long)(c0 + ty + 8*i) * rows + r0 + tx] = f2bf(t[tx][ty + 8*i]);
}

// ---------------- GEMM core: C[128x128] tile, K=512, BK=32, bf16 (R4-proven) ----------------
// T4 counted-vmcnt pipeline: quad-buffered LDS (4 x 8KB per operand), stage 2 tiles ahead,
// ONE raw s_barrier per K-step, s_waitcnt vmcnt(8) in steady state (never 0 until drain).
// LDS chunk-XOR swizzle (chunk ^= (row>>1)&3) via pre-swizzled GLOBAL source + swizzled read.
static __device__ __forceinline__ void stage_tile(const u16* __restrict__ Ag, const u16* __restrict__ Bg,
                                                  u16* At, u16* Bt, int bm, int bn, int k0){
  const int tid = threadIdx.x, wave = tid >> 6, lane = tid & 63;
  #pragma unroll
  for (int j = 0; j < 2; j++){
    int ca = wave*128 + j*64 + lane;         // 16B-chunk id 0..511 (LDS dest = ca*16B, linear)
    int row = ca >> 2;
    int c8 = (((ca & 3) ^ ((ca >> 3) & 3)) * 8);   // pre-swizzled source column
    int ga = bm*128 + row; ga = ga < RTOK ? ga : RTOK - 1;   // clamp last tile
    g2l16(Ag + (long)ga*512 + k0 + c8, At + wave*1024 + j*512);
    g2l16(Bg + (long)(bn*128 + row)*512 + k0 + c8, Bt + wave*1024 + j*512);
  }
}

static __device__ __forceinline__ void gemm_compute(const u16* Ac, const u16* Bc, f32x4 (&acc)[4][4],
                                                    int wave, int quad, int l15){
  const int r0 = (wave >> 1) * 64, c0 = (wave & 1) * 64;
  const int pc = quad ^ ((l15 >> 1) & 3);    // physical chunk (row-dependent swizzle)
  bf16x8 af[4], bfr[4];
  #pragma unroll
  for (int mt = 0; mt < 4; mt++) af[mt]  = *(const bf16x8*)(Ac + (r0 + mt*16 + l15)*32 + pc*8);
  #pragma unroll
  for (int nt = 0; nt < 4; nt++) bfr[nt] = *(const bf16x8*)(Bc + (c0 + nt*16 + l15)*32 + pc*8);
  #pragma unroll
  for (int mt = 0; mt < 4; mt++)
    #pragma unroll
    for (int nt = 0; nt < 4; nt++)
      acc[mt][nt] = __builtin_amdgcn_mfma_f32_16x16x32_bf16(af[mt], bfr[nt], acc[mt][nt], 0, 0, 0);
}

static __device__ __forceinline__ void gemm_core(const u16* __restrict__ Ag, const u16* __restrict__ Bg,
                                                 u16* At, u16* Bt, int bm, int bn, f32x4 (&acc)[4][4]){
  // At/Bt are [4][128*32] u16 quad buffers (4096 u16 = 8KB per tile each)
  const int tid = threadIdx.x, wave = tid >> 6, lane = tid & 63, quad = lane >> 4, l15 = lane & 15;
  stage_tile(Ag, Bg, At, Bt, bm, bn, 0);                    // tile 0
  stage_tile(Ag, Bg, At + 4096, Bt + 4096, bm, bn, 32);     // tile 1
  #pragma unroll
  for (int t = 0; t < 16; ++t){
    if (t + 2 < 16)
      stage_tile(Ag, Bg, At + ((t+2)&3)*4096, Bt + ((t+2)&3)*4096, bm, bn, (t+2)*32);
    __builtin_amdgcn_sched_barrier(0);        // pin stage-issue above the counted wait
    if (t < 14)       asm volatile("s_waitcnt vmcnt(8)" ::: "memory");   // tile t landed; t+1,t+2 in flight
    else if (t == 14) asm volatile("s_waitcnt vmcnt(4)" ::: "memory");
    else              asm volatile("s_waitcnt vmcnt(0)" ::: "memory");
    __builtin_amdgcn_sched_barrier(0);        // nothing hoists above the wait
    __builtin_amdgcn_s_barrier();             // raw barrier: NO vmcnt(0) drain
    __builtin_amdgcn_sched_barrier(0);        // ds_reads stay below the barrier
    gemm_compute(At + (t&3)*4096, Bt + (t&3)*4096, acc, wave, quad, l15);
  }
}

// ---------------- QKV GEMM: xb @ wqkv^T, scatter to q/k/v [bh][n][64] bf16, q*0.125 ----------------
__global__ __launch_bounds__(256) void gemm_qkv(const u16* __restrict__ X, const u16* __restrict__ WT,
                                                u16* __restrict__ qb, u16* __restrict__ kb, u16* __restrict__ vb){
  __shared__ __attribute__((aligned(16))) u16 At[4*128*32];
  __shared__ __attribute__((aligned(16))) u16 Bt[4*128*32];
  const int tid = threadIdx.x, wave = tid >> 6, quad = (tid & 63) >> 4, l15 = tid & 15;
  const int id = blockIdx.x;
  const int logical = (id & 7) * 297 + (id >> 3);   // 2376/8 = 297, bijective
  const int bm = logical / 12, bn = logical % 12;
  f32x4 acc[4][4] = {};
  gemm_core(X, WT, At, Bt, bm, bn, acc);
  const int rbase = bm*128 + (wave >> 1)*64;
  const int cbase = bn*128 + (wave & 1)*64;
  // cbase is a multiple of 64 -> target tensor t and head index are wave-uniform
  const int t = cbase >> 9;
  const int head = (cbase & 511) >> 6;
  u16* __restrict__ dst = (t == 0) ? qb : ((t == 1) ? kb : vb);
  const float scl = (t == 0) ? 0.125f : 1.0f;
  #pragma unroll
  for (int mt = 0; mt < 4; mt++)
  #pragma unroll
  for (int r = 0; r < 4; r++){
    int row = rbase + mt*16 + quad*4 + r;
    if (row < RTOK){
      int b = row / N_, n = row - b * N_;
      long base = ((long)(b*8 + head) * N_ + n) * 64;
      #pragma unroll
      for (int nt = 0; nt < 4; nt++)
        dst[base + nt*16 + l15] = f2bf(acc[mt][nt][r] * scl);
    }
  }
}

// ---------------- OUT GEMM: aob @ wout^T + b_out -> d_out (fp32) ----------------
__global__ __launch_bounds__(256) void gemm_out(const u16* __restrict__ A, const u16* __restrict__ WT,
                                                const float* __restrict__ bias, float* __restrict__ out){
  __shared__ __attribute__((aligned(16))) u16 At[4*128*32];
  __shared__ __attribute__((aligned(16))) u16 Bt[4*128*32];
  const int tid = threadIdx.x, wave = tid >> 6, quad = (tid & 63) >> 4, l15 = tid & 15;
  const int id = blockIdx.x;
  const int logical = (id & 7) * 99 + (id >> 3);    // 792/8 = 99, bijective
  const int bm = logical >> 2, bn = logical & 3;
  f32x4 acc[4][4] = {};
  gemm_core(A, WT, At, Bt, bm, bn, acc);
  const int rbase = bm*128 + (wave >> 1)*64;
  const int cbase = bn*128 + (wave & 1)*64;
  #pragma unroll
  for (int mt = 0; mt < 4; mt++)
  #pragma unroll
  for (int nt = 0; nt < 4; nt++)
  #pragma unroll
  for (int r = 0; r < 4; r++){
    int row = rbase + mt*16 + quad*4 + r;
    if (row < RTOK){
      int col = cbase + nt*16 + l15;
      out[(long)row*512 + col] = acc[mt][nt][r] + bias[col];
    }
  }
}

// ---------------- joint attention, key-split partials: grid (64, JSPLIT) ----------------
// LDS bank-conflict fix this round: Kc/Qj (128B rows) and Vt (256B rows) XOR-swizzled
// byte ^= (row&7)<<4 ; Pl (256B rows) byte ^= (row&3)<<4 ; Oacc padded to 65 floats/row.
// All 16-way fragment-read conflicts -> 2-4 way.
__global__ __launch_bounds__(256) void joint_part(const u16* __restrict__ qb, const u16* __restrict__ kb,
                                                  const u16* __restrict__ vb, float* __restrict__ po,
                                                  float* __restrict__ pm, float* __restrict__ pl){
  __shared__ __attribute__((aligned(16))) u16 Qj[32*64];
  __shared__ __attribute__((aligned(16))) u16 Kc[128*64];
  __shared__ __attribute__((aligned(16))) u16 Vt[64*128];
  __shared__ __attribute__((aligned(16))) u16 Pl[32*128];
  __shared__ float redm[4][32];
  __shared__ float redl[4][32];
  __shared__ float mrow[32], lrow[32], arow[32];
  __shared__ float Oacc[32*65];
  const int tid = threadIdx.x, wave = tid >> 6, lane = tid & 63, quad = lane >> 4, l15 = lane & 15;
  const int bh = blockIdx.x, split = blockIdx.y;
  const int kbeg = split * 256;
  const int kend = (kbeg + 256 < N_) ? kbeg + 256 : N_;
  const u16* kbh = kb + (long)bh * N_ * 64;
  const u16* vbh = vb + (long)bh * N_ * 64;
  const u16* qbh = qb + (long)bh * N_ * 64;
  { // stage Qj swizzled (rows 24..31 zero)
    int row = tid >> 3, c8 = (tid & 7) * 8;
    us8 z;
    #pragma unroll
    for (int i = 0; i < 8; i++) z[i] = 0;
    us8 v = (row < J_) ? *(const us8*)(qbh + row*64 + c8) : z;
    *(us8*)((char*)Qj + (((row << 7) + c8*2) ^ ((row & 7) << 4))) = v;
  }
  if (tid < 32){ mrow[tid] = -1e30f; lrow[tid] = 0.f; }
  f32x4 o[2][4] = {};
  __syncthreads();
  for (int c0 = kbeg; c0 < kend; c0 += 128){
    // stage K chunk swizzled (clamped rows; masked later)
    #pragma unroll
    for (int it = 0; it < 4; ++it){
      int j = tid + it*256;
      int row = j >> 3, c8 = (j & 7) * 8;
      int gr = c0 + row; gr = gr < N_ ? gr : N_ - 1;
      *(us8*)((char*)Kc + (((row << 7) + c8*2) ^ ((row & 7) << 4))) =
          *(const us8*)(kbh + (long)gr*64 + c8);
    }
    { // stage V^T swizzled: 2 threads per key-column (conflict-free u16 scatter)
      int row = tid >> 1, dh = (tid & 1) * 32;
      int gr = c0 + row; gr = gr < N_ ? gr : N_ - 1;
      const u16* src = vbh + (long)gr*64 + dh;
      #pragma unroll
      for (int d0 = 0; d0 < 32; d0 += 8){
        us8 vv = *(const us8*)(src + d0);
        #pragma unroll
        for (int i = 0; i < 8; i++){
          int d = dh + d0 + i;
          *(u16*)((char*)Vt + (((d << 8) + row*2) ^ ((d & 7) << 4))) = vv[i];
        }
      }
    }
    __syncthreads();
    // QK^T for this wave's 32 keys
    f32x4 sim[2][2];
    #pragma unroll
    for (int mt = 0; mt < 2; mt++){
      int arow_i = mt*16 + l15;
      bf16x8 a0 = *(const bf16x8*)((const char*)Qj + (((arow_i << 7) + quad*16)      ^ ((arow_i & 7) << 4)));
      bf16x8 a1 = *(const bf16x8*)((const char*)Qj + (((arow_i << 7) + 64 + quad*16) ^ ((arow_i & 7) << 4)));
      #pragma unroll
      for (int ntl = 0; ntl < 2; ntl++){
        int krow = wave*32 + ntl*16 + l15;
        bf16x8 b0 = *(const bf16x8*)((const char*)Kc + (((krow << 7) + quad*16)      ^ ((krow & 7) << 4)));
        bf16x8 b1 = *(const bf16x8*)((const char*)Kc + (((krow << 7) + 64 + quad*16) ^ ((krow & 7) << 4)));
        f32x4 s = {0.f, 0.f, 0.f, 0.f};
        s = __builtin_amdgcn_mfma_f32_16x16x32_bf16(a0, b0, s, 0, 0, 0);
        s = __builtin_amdgcn_mfma_f32_16x16x32_bf16(a1, b1, s, 0, 0, 0);
        if (c0 + krow >= N_){
          #pragma unroll
          for (int r = 0; r < 4; r++) s[r] = -1e30f;
        }
        sim[mt][ntl] = s;
      }
    }
    // per-row partial max (over this wave's keys)
    #pragma unroll
    for (int mt = 0; mt < 2; mt++)
    #pragma unroll
    for (int r = 0; r < 4; r++){
      float m = fmaxf(sim[mt][0][r], sim[mt][1][r]);
      #pragma unroll
      for (int sh = 1; sh < 16; sh <<= 1) m = fmaxf(m, __shfl_xor(m, sh, 64));
      if (l15 == 0) redm[wave][mt*16 + quad*4 + r] = m;
    }
    __syncthreads();
    if (tid < 32){
      float cm = fmaxf(fmaxf(redm[0][tid], redm[1][tid]), fmaxf(redm[2][tid], redm[3][tid]));
      float nm = fmaxf(mrow[tid], cm);
      arow[tid] = __expf(mrow[tid] - nm);
      mrow[tid] = nm;
    }
    __syncthreads();
    // p = exp(sim - m), write P (swizzled), partial sums, rescale O
    #pragma unroll
    for (int mt = 0; mt < 2; mt++)
    #pragma unroll
    for (int r = 0; r < 4; r++){
      int rowi = mt*16 + quad*4 + r;
      float nm = mrow[rowi];
      float p0 = __expf(sim[mt][0][r] - nm);
      float p1 = __expf(sim[mt][1][r] - nm);
      float s = p0 + p1;
      #pragma unroll
      for (int sh = 1; sh < 16; sh <<= 1) s += __shfl_xor(s, sh, 64);
      if (l15 == 0) redl[wave][rowi] = s;
      *(u16*)((char*)Pl + (((rowi << 8) + wave*64 + l15*2)      ^ ((rowi & 3) << 4))) = f2bf(p0);
      *(u16*)((char*)Pl + (((rowi << 8) + wave*64 + 32 + l15*2) ^ ((rowi & 3) << 4))) = f2bf(p1);
      float al = arow[rowi];
      #pragma unroll
      for (int ntd = 0; ntd < 4; ntd++) o[mt][ntd][r] *= al;
    }
    __syncthreads();
    if (tid < 32)
      lrow[tid] = lrow[tid]*arow[tid] + redl[0][tid] + redl[1][tid] + redl[2][tid] + redl[3][tid];
    // PV: this wave's 32 keys (swizzled Pl / Vt reads)
    #pragma unroll
    for (int mt = 0; mt < 2; mt++){
      int prow = mt*16 + l15;
      bf16x8 ap = *(const bf16x8*)((const char*)Pl + (((prow << 8) + wave*64 + quad*16) ^ ((prow & 3) << 4)));
      #pragma unroll
      for (int ntd = 0; ntd < 4; ntd++){
        int vrow = ntd*16 + l15;
        bf16x8 bv = *(const bf16x8*)((const char*)Vt + (((vrow << 8) + wave*64 + quad*16) ^ ((vrow & 7) << 4)));
        o[mt][ntd] = __builtin_amdgcn_mfma_f32_16x16x32_bf16(ap, bv, o[mt][ntd], 0, 0, 0);
      }
    }
    __syncthreads();
  }
  // merge wave partials
  #pragma unroll 1
  for (int w = 0; w < 4; ++w){
    if (wave == w){
      #pragma unroll
      for (int mt = 0; mt < 2; mt++)
      #pragma unroll
      for (int ntd = 0; ntd < 4; ntd++)
      #pragma unroll
      for (int r = 0; r < 4; r++){
        int rowi = mt*16 + quad*4 + r, d = ntd*16 + l15;
        if (w == 0) Oacc[rowi*65 + d]  = o[mt][ntd][r];
        else        Oacc[rowi*65 + d] += o[mt][ntd][r];
      }
    }
    __syncthreads();
  }
  const long pbase = (long)(bh*JSPLIT + split) * J_;
  for (int j = tid; j < J_*64; j += 256){
    int row = j >> 6, d = j & 63;
    po[(pbase + row)*64 + d] = Oacc[row*65 + d];
  }
  if (tid < J_){ pm[pbase + tid] = mrow[tid]; pl[pbase + tid] = lrow[tid]; }
}

// ---------------- joint merge: combine JSPLIT partials per bh ----------------
__global__ __launch_bounds__(256) void joint_merge(const float* __restrict__ po, const float* __restrict__ pm,
                                                   const float* __restrict__ pl, u16* __restrict__ ao){
  __shared__ float sc[JSPLIT][J_];
  __shared__ float lg[J_];
  const int tid = threadIdx.x, bh = blockIdx.x;
  if (tid < J_){
    float m = -1e30f;
    #pragma unroll
    for (int s = 0; s < JSPLIT; s++) m = fmaxf(m, pm[(bh*JSPLIT + s)*J_ + tid]);
    float l = 0.f;
    #pragma unroll
    for (int s = 0; s < JSPLIT; s++){
      float e = __expf(pm[(bh*JSPLIT + s)*J_ + tid] - m);
      sc[s][tid] = e;
      l += pl[(bh*JSPLIT + s)*J_ + tid] * e;
    }
    lg[tid] = l;
  }
  __syncthreads();
  const int b = bh >> 3, h = bh & 7;
  for (int j = tid; j < J_*64; j += 256){
    int row = j >> 6, d = j & 63;
    float acc = 0.f;
    #pragma unroll
    for (int s = 0; s < JSPLIT; s++)
      acc += po[((long)(bh*JSPLIT + s)*J_ + row)*64 + d] * sc[s][row];
    ao[((long)(b*N_ + row))*512 + h*64 + d] = f2bf(acc / lg[row]);
  }
}

// ---------------- spatial attention: per (bh,f), 196 q vs 220 keys, RoPE fused ----------------
__global__ __launch_bounds__(256, 2) void spatial_attn(const u16* __restrict__ qb, const u16* __restrict__ kb,
                                                    const u16* __restrict__ vb, const float* __restrict__ sinb,
                                                    const float* __restrict__ cosb, u16* __restrict__ ao){
  __shared__ __attribute__((aligned(16))) u16 Kl[224*64];
  __shared__ __attribute__((aligned(16))) u16 Vt[64*256];
  __shared__ __attribute__((aligned(16))) u16 Pl[4*16*32];
  const int tid = threadIdx.x, wave = tid >> 6, lane = tid & 63, quad = lane >> 4, l15 = lane & 15;
  const int bh = blockIdx.x >> 4, f = blockIdx.x & 15;
  const u16* kbh = kb + (long)bh * N_ * 64;
  const u16* vbh = vb + (long)bh * N_ * 64;
  const u16* qbh = qb + (long)bh * N_ * 64 + (long)(J_ + f*NS_) * 64;
  // stage K rows 0..223, swizzled (rows 24..219 get RoPE on dims<32; rows 220..223 zeroed)
  for (int j = tid; j < 224*8; j += 256){
    int n = j >> 3, c8 = (j & 7) * 8;
    us8 kv;
    if (n < SKEY){
      kv = *(const us8*)(kbh + (long)((n < J_) ? n : n + f*NS_) * 64 + c8);
      if (n >= J_ && c8 < 32){
        int ns = n - J_;
        kv = rope8(kv, sinb + ns*32 + c8, cosb + ns*32 + c8);
      }
    } else {
      #pragma unroll
      for (int i = 0; i < 8; i++) kv[i] = 0;
    }
    *(us8*)((char*)Kl + (((n << 7) + c8*2) ^ ((n & 7) << 4))) = kv;
  }
  // stage V^T swizzled: thread t owns key-column n = t
  if (tid < 224){
    const int n = tid;
    const bool valid = n < SKEY;
    const u16* src = vbh + (long)((n < J_) ? n : n + f*NS_) * 64;
    #pragma unroll
    for (int d0 = 0; d0 < 64; d0 += 8){
      us8 vv;
      if (valid) vv = *(const us8*)(src + d0);
      else {
        #pragma unroll
        for (int i = 0; i < 8; i++) vv[i] = 0;
      }
      #pragma unroll
      for (int i = 0; i < 8; i++){
        int d = d0 + i;
        *(u16*)((char*)Vt + (((d << 9) + n*2) ^ ((d & 7) << 4))) = vv[i];
      }
    }
  }
  __syncthreads();
  const int b = bh >> 3, h = bh & 7;
  #pragma unroll 1
  for (int mt = 0; mt < 4; ++mt){
    int qrow = wave*64 + mt*16 + l15;
    int qi = qrow < NS_ ? qrow : NS_ - 1;           // clamp padded rows (stores guarded)
    U8 a0u, a1u;
    a0u.u = *(const us8*)(qbh + (long)qi*64 + quad*8);
    a0u.u = rope8(a0u.u, sinb + qi*32 + quad*8, cosb + qi*32 + quad*8);
    a1u.u = *(const us8*)(qbh + (long)qi*64 + 32 + quad*8);
    f32x4 sim[14];
    #pragma unroll
    for (int nt = 0; nt < 14; ++nt){
      int krow = nt*16 + l15;
      bf16x8 b0 = *(const bf16x8*)((const char*)Kl + (((krow << 7) + quad*16)      ^ ((krow & 7) << 4)));
      bf16x8 b1 = *(const bf16x8*)((const char*)Kl + (((krow << 7) + 64 + quad*16) ^ ((krow & 7) << 4)));
      f32x4 s = {0.f, 0.f, 0.f, 0.f};
      s = __builtin_amdgcn_mfma_f32_16x16x32_bf16(a0u.b, b0, s, 0, 0, 0);
      s = __builtin_amdgcn_mfma_f32_16x16x32_bf16(a1u.b, b1, s, 0, 0, 0);
      sim[nt] = s;
    }
    if (l15 >= 12){  // keys 220..223 are padding
      #pragma unroll
      for (int r = 0; r < 4; r++) sim[13][r] = -1e30f;
    }
    // full softmax in registers (rows live in quads; reduce over 16 lanes)
    #pragma unroll
    for (int r = 0; r < 4; r++){
      float m = sim[0][r];
      #pragma unroll
      for (int nt = 1; nt < 14; nt++) m = fmaxf(m, sim[nt][r]);
      #pragma unroll
      for (int sh = 1; sh < 16; sh <<= 1) m = fmaxf(m, __shfl_xor(m, sh, 64));
      float s = 0.f;
      #pragma unroll
      for (int nt = 0; nt < 14; nt++){ float p = __expf(sim[nt][r] - m); sim[nt][r] = p; s += p; }
      #pragma unroll
      for (int sh = 1; sh < 16; sh <<= 1) s += __shfl_xor(s, sh, 64);
      float inv = 1.f / s;
      #pragma unroll
      for (int nt = 0; nt < 14; nt++) sim[nt][r] *= inv;
    }
    // PV in 7 chunks of 32 keys; P round-trip through per-wave LDS (no block barrier needed).
    f32x4 o[4] = {};
    u16* pw = Pl + wave*512;
    #pragma unroll
    for (int c = 0; c < 7; c++){
      #pragma unroll
      for (int h2 = 0; h2 < 2; h2++){
        #pragma unroll
        for (int r = 0; r < 4; r++)
          pw[(quad*4 + r)*32 + h2*16 + l15] = f2bf(sim[2*c + h2][r]);
      }
      __builtin_amdgcn_wave_barrier();
      bf16x8 ap = *(const bf16x8*)(pw + l15*32 + quad*8);
      #pragma unroll
      for (int ntd = 0; ntd < 4; ntd++){
        int vrow = ntd*16 + l15;
        bf16x8 bv = *(const bf16x8*)((const char*)Vt + (((vrow << 9) + c*64 + quad*16) ^ ((vrow & 7) << 4)));
        o[ntd] = __builtin_amdgcn_mfma_f32_16x16x32_bf16(ap, bv, o[ntd], 0, 0, 0);
      }
      __builtin_amdgcn_wave_barrier();
    }
    #pragma unroll
    for (int ntd = 0; ntd < 4; ntd++)
    #pragma unroll
    for (int r = 0; r < 4; r++){
      int qr = wave*64 + mt*16 + quad*4 + r;
      if (qr < NS_){
        int n = J_ + f*NS_ + qr;
        ao[((long)(b*N_ + n))*512 + h*64 + ntd*16 + l15] = f2bf(o[ntd][r]);
      }
    }
  }
}

extern "C" void kernel_launch(void* const* d_in, const int* in_sizes, int n_in,
                              void* d_out, int out_size, void* d_ws, size_t ws_size,
                              hipStream_t stream){
  (void)in_sizes; (void)n_in; (void)out_size; (void)ws_size;
  const float* x    = (const float*)d_in[0];
  const float* wqkv = (const float*)d_in[1];
  const float* wout = (const float*)d_in[2];
  const float* bout = (const float*)d_in[3];
  const float* sinb = (const float*)d_in[4];
  const float* cosb = (const float*)d_in[5];
  float* out = (float*)d_out;
  u16* ws  = (u16*)d_ws;
  u16* qb  = ws;                       // [64][3160][64] bf16
  u16* kb  = qb  + 12943360;
  u16* vb  = kb  + 12943360;
  u16* xb  = vb  + 12943360;           // x bf16 [25280][512]; later reused as aob [B][N][512]
  u16* aob = xb;                       //   (alias: xb dead after gemm_qkv)
  u16* wt1 = xb  + 12943360;           // w_qkv^T bf16 [1536][512]
  u16* wt2 = wt1 + 786432;             // w_out^T bf16 [512][512]
  float* po = (float*)(wt2 + 262144);  // [64][JSPLIT][24][64] fp32 partial O
  float* pm = po + 64*JSPLIT*J_*64;    // [64][JSPLIT][24]
  float* pl = pm + 64*JSPLIT*J_;
  cvt_bf16<<<dim3((12943360/4 + 255)/256), 256, 0, stream>>>(x, xb, 12943360/4);
  ktranspose2<<<dim3(64, 16), 256, 0, stream>>>(wqkv, wt1, wout, wt2);
  gemm_qkv<<<dim3(2376), 256, 0, stream>>>(xb, wt1, qb, kb, vb);
  joint_part<<<dim3(64, JSPLIT), 256, 0, stream>>>(qb, kb, vb, po, pm, pl);
  joint_merge<<<dim3(64), 256, 0, stream>>>(po, pm, pl, aob);
  spatial_attn<<<dim3(1024), 256, 0, stream>>>(qb, kb, vb, sinb, cosb, aob);
  gemm_out<<<dim3(792), 256, 0, stream>>>(aob, wt2, bout, out);
}

// Round 8
// 294.911 us; speedup vs baseline: 1.2138x; 1.0292x over previous
//
#include <hip/hip_runtime.h>
#include <stdint.h>

typedef unsigned short u16;
typedef __bf16 bf16x8 __attribute__((ext_vector_type(8)));
typedef float f32x4 __attribute__((ext_vector_type(4)));
typedef unsigned short us8 __attribute__((ext_vector_type(8)));
typedef unsigned short us4 __attribute__((ext_vector_type(4)));

#define B_ 8
#define F_ 16
#define NS_ 196
#define J_ 24
#define H_ 8
#define N_ 3160
#define RTOK 25280   // B_*N_
#define SKEY 220     // J_+NS_
#define JSPLIT 13    // ceil(3160/256) key-splits for joint attention

union U8 { us8 u; bf16x8 b; };

static __device__ __forceinline__ float bf2f(u16 v){
  unsigned int u = ((unsigned int)v) << 16; float f; __builtin_memcpy(&f, &u, 4); return f;
}
static __device__ __forceinline__ u16 f2bf(float f){
  unsigned int u; __builtin_memcpy(&u, &f, 4);
  u = (u + 0x7fffu + ((u >> 16) & 1u)) >> 16; return (u16)u;
}
static __device__ __forceinline__ void g2l16(const u16* g, u16* l){
  __builtin_amdgcn_global_load_lds((const __attribute__((address_space(1))) void*)g,
                                   (__attribute__((address_space(3))) void*)l, 16, 0, 0);
}
// RoPE on 8 bf16 elems with fp32 sin/cos
static __device__ __forceinline__ us8 rope8(us8 t, const float* __restrict__ sv,
                                            const float* __restrict__ cv){
  us8 o;
  #pragma unroll
  for (int i = 0; i < 8; i += 2){
    float e0 = bf2f(t[i]), e1 = bf2f(t[i+1]);
    o[i]   = f2bf(e0 * cv[i]   - e1 * sv[i]);
    o[i+1] = f2bf(e1 * cv[i+1] + e0 * sv[i+1]);
  }
  return o;
}

// ---------------- prep: fused fp32->bf16 convert (x) + both weight transposes ----------------
// grid 13664 = 12640 cvt blocks + 1024 transpose blocks (executes under the cvt memory stream).
__global__ __launch_bounds__(256) void prep(const float* __restrict__ src, u16* __restrict__ dst, int n4,
                                            const float* __restrict__ s1, u16* __restrict__ d1,
                                            const float* __restrict__ s2, u16* __restrict__ d2){
  __shared__ float t[32][33];
  const int bid = blockIdx.x;
  if (bid < 12640){
    int i = bid * 256 + threadIdx.x;
    if (i < n4){
      float4 v = ((const float4*)src)[i];
      us4 o; o[0] = f2bf(v.x); o[1] = f2bf(v.y); o[2] = f2bf(v.z); o[3] = f2bf(v.w);
      ((us4*)dst)[i] = o;
    }
  } else {
    const int kbid = bid - 12640;          // 0..1023 -> (bx 0..63, by 0..15)
    const int bx = kbid & 63, by = kbid >> 6;
    const float* ksrc; u16* kdst; int cols; int c0;
    if (bx < 48){ ksrc = s1; kdst = d1; cols = 1536; c0 = bx*32; }
    else        { ksrc = s2; kdst = d2; cols = 512;  c0 = (bx-48)*32; }
    const int rows = 512;
    int tx = threadIdx.x & 31, ty = threadIdx.x >> 5;
    int r0 = by * 32;
    #pragma unroll
    for (int i = 0; i < 4; i++) t[ty + 8*i][tx] = ksrc[(long)(r0 + ty + 8*i) * cols + c0 + tx];
    __syncthreads();
    #pragma unroll
    for (int i = 0; i < 4; i++) kdst[(long)(c0 + ty + 8*i) * rows + r0 + tx] = f2bf(t[tx][ty + 8*i]);
  }
}

// ---------------- GEMM core: C[128x128] tile, K=512, BK=32, bf16 (R6-proven) ----------------
// T4 counted-vmcnt pipeline: quad-buffered LDS (4 x 8KB per operand), stage 2 tiles ahead,
// ONE raw s_barrier per K-step, s_waitcnt vmcnt(8) in steady state (never 0 until drain).
// LDS chunk-XOR swizzle (chunk ^= (row>>1)&3) via pre-swizzled GLOBAL source + swizzled read.
static __device__ __forceinline__ void stage_tile(const u16* __restrict__ Ag, const u16* __restrict__ Bg,
                                                  u16* At, u16* Bt, int bm, int bn, int k0){
  const int tid = threadIdx.x, wave = tid >> 6, lane = tid & 63;
  #pragma unroll
  for (int j = 0; j < 2; j++){
    int ca = wave*128 + j*64 + lane;         // 16B-chunk id 0..511 (LDS dest = ca*16B, linear)
    int row = ca >> 2;
    int c8 = (((ca & 3) ^ ((ca >> 3) & 3)) * 8);   // pre-swizzled source column
    int ga = bm*128 + row; ga = ga < RTOK ? ga : RTOK - 1;   // clamp last tile
    g2l16(Ag + (long)ga*512 + k0 + c8, At + wave*1024 + j*512);
    g2l16(Bg + (long)(bn*128 + row)*512 + k0 + c8, Bt + wave*1024 + j*512);
  }
}

static __device__ __forceinline__ void gemm_compute(const u16* Ac, const u16* Bc, f32x4 (&acc)[4][4],
                                                    int wave, int quad, int l15){
  const int r0 = (wave >> 1) * 64, c0 = (wave & 1) * 64;
  const int pc = quad ^ ((l15 >> 1) & 3);    // physical chunk (row-dependent swizzle)
  bf16x8 af[4], bfr[4];
  #pragma unroll
  for (int mt = 0; mt < 4; mt++) af[mt]  = *(const bf16x8*)(Ac + (r0 + mt*16 + l15)*32 + pc*8);
  #pragma unroll
  for (int nt = 0; nt < 4; nt++) bfr[nt] = *(const bf16x8*)(Bc + (c0 + nt*16 + l15)*32 + pc*8);
  #pragma unroll
  for (int mt = 0; mt < 4; mt++)
    #pragma unroll
    for (int nt = 0; nt < 4; nt++)
      acc[mt][nt] = __builtin_amdgcn_mfma_f32_16x16x32_bf16(af[mt], bfr[nt], acc[mt][nt], 0, 0, 0);
}

static __device__ __forceinline__ void gemm_core(const u16* __restrict__ Ag, const u16* __restrict__ Bg,
                                                 u16* At, u16* Bt, int bm, int bn, f32x4 (&acc)[4][4]){
  // At/Bt are [4][128*32] u16 quad buffers (4096 u16 = 8KB per tile each)
  const int tid = threadIdx.x, wave = tid >> 6, lane = tid & 63, quad = lane >> 4, l15 = lane & 15;
  stage_tile(Ag, Bg, At, Bt, bm, bn, 0);                    // tile 0
  stage_tile(Ag, Bg, At + 4096, Bt + 4096, bm, bn, 32);     // tile 1
  #pragma unroll
  for (int t = 0; t < 16; ++t){
    if (t + 2 < 16)
      stage_tile(Ag, Bg, At + ((t+2)&3)*4096, Bt + ((t+2)&3)*4096, bm, bn, (t+2)*32);
    __builtin_amdgcn_sched_barrier(0);        // pin stage-issue above the counted wait
    if (t < 14)       asm volatile("s_waitcnt vmcnt(8)" ::: "memory");   // tile t landed; t+1,t+2 in flight
    else if (t == 14) asm volatile("s_waitcnt vmcnt(4)" ::: "memory");
    else              asm volatile("s_waitcnt vmcnt(0)" ::: "memory");
    __builtin_amdgcn_sched_barrier(0);        // nothing hoists above the wait
    __builtin_amdgcn_s_barrier();             // raw barrier: NO vmcnt(0) drain
    __builtin_amdgcn_sched_barrier(0);        // ds_reads stay below the barrier
    gemm_compute(At + (t&3)*4096, Bt + (t&3)*4096, acc, wave, quad, l15);
  }
}

// ---------------- QKV GEMM: xb @ wqkv^T, scatter to q/k/v [bh][n][64] bf16, q*0.125 ----------------
__global__ __launch_bounds__(256) void gemm_qkv(const u16* __restrict__ X, const u16* __restrict__ WT,
                                                u16* __restrict__ qb, u16* __restrict__ kb, u16* __restrict__ vb){
  __shared__ __attribute__((aligned(16))) u16 At[4*128*32];
  __shared__ __attribute__((aligned(16))) u16 Bt[4*128*32];
  const int tid = threadIdx.x, wave = tid >> 6, quad = (tid & 63) >> 4, l15 = tid & 15;
  const int id = blockIdx.x;
  const int logical = (id & 7) * 297 + (id >> 3);   // 2376/8 = 297, bijective
  const int bm = logical / 12, bn = logical % 12;
  f32x4 acc[4][4] = {};
  gemm_core(X, WT, At, Bt, bm, bn, acc);
  const int rbase = bm*128 + (wave >> 1)*64;
  const int cbase = bn*128 + (wave & 1)*64;
  // cbase is a multiple of 64 -> target tensor t and head index are wave-uniform
  const int t = cbase >> 9;
  const int head = (cbase & 511) >> 6;
  u16* __restrict__ dst = (t == 0) ? qb : ((t == 1) ? kb : vb);
  const float scl = (t == 0) ? 0.125f : 1.0f;
  #pragma unroll
  for (int mt = 0; mt < 4; mt++)
  #pragma unroll
  for (int r = 0; r < 4; r++){
    int row = rbase + mt*16 + quad*4 + r;
    if (row < RTOK){
      int b = row / N_, n = row - b * N_;
      long base = ((long)(b*8 + head) * N_ + n) * 64;
      #pragma unroll
      for (int nt = 0; nt < 4; nt++)
        dst[base + nt*16 + l15] = f2bf(acc[mt][nt][r] * scl);
    }
  }
}

// ---------------- OUT GEMM: aob @ wout^T + b_out -> d_out (fp32) ----------------
__global__ __launch_bounds__(256) void gemm_out(const u16* __restrict__ A, const u16* __restrict__ WT,
                                                const float* __restrict__ bias, float* __restrict__ out){
  __shared__ __attribute__((aligned(16))) u16 At[4*128*32];
  __shared__ __attribute__((aligned(16))) u16 Bt[4*128*32];
  const int tid = threadIdx.x, wave = tid >> 6, quad = (tid & 63) >> 4, l15 = tid & 15;
  const int id = blockIdx.x;
  const int logical = (id & 7) * 99 + (id >> 3);    // 792/8 = 99, bijective
  const int bm = logical >> 2, bn = logical & 3;
  f32x4 acc[4][4] = {};
  gemm_core(A, WT, At, Bt, bm, bn, acc);
  const int rbase = bm*128 + (wave >> 1)*64;
  const int cbase = bn*128 + (wave & 1)*64;
  #pragma unroll
  for (int mt = 0; mt < 4; mt++)
  #pragma unroll
  for (int nt = 0; nt < 4; nt++)
  #pragma unroll
  for (int r = 0; r < 4; r++){
    int row = rbase + mt*16 + quad*4 + r;
    if (row < RTOK){
      int col = cbase + nt*16 + l15;
      out[(long)row*512 + col] = acc[mt][nt][r] + bias[col];
    }
  }
}

// ---------------- joint attention, key-split partials: grid (64, JSPLIT) ----------------
// Kc/Qj/Vt XOR-swizzled (byte ^= (row&7)<<4), Pl ^= (row&3)<<4, Oacc padded (R6-proven).
__global__ __launch_bounds__(256) void joint_part(const u16* __restrict__ qb, const u16* __restrict__ kb,
                                                  const u16* __restrict__ vb, float* __restrict__ po,
                                                  float* __restrict__ pm, float* __restrict__ pl){
  __shared__ __attribute__((aligned(16))) u16 Qj[32*64];
  __shared__ __attribute__((aligned(16))) u16 Kc[128*64];
  __shared__ __attribute__((aligned(16))) u16 Vt[64*128];
  __shared__ __attribute__((aligned(16))) u16 Pl[32*128];
  __shared__ float redm[4][32];
  __shared__ float redl[4][32];
  __shared__ float mrow[32], lrow[32], arow[32];
  __shared__ float Oacc[32*65];
  const int tid = threadIdx.x, wave = tid >> 6, lane = tid & 63, quad = lane >> 4, l15 = lane & 15;
  const int bh = blockIdx.x, split = blockIdx.y;
  const int kbeg = split * 256;
  const int kend = (kbeg + 256 < N_) ? kbeg + 256 : N_;
  const u16* kbh = kb + (long)bh * N_ * 64;
  const u16* vbh = vb + (long)bh * N_ * 64;
  const u16* qbh = qb + (long)bh * N_ * 64;
  { // stage Qj swizzled (rows 24..31 zero)
    int row = tid >> 3, c8 = (tid & 7) * 8;
    us8 z;
    #pragma unroll
    for (int i = 0; i < 8; i++) z[i] = 0;
    us8 v = (row < J_) ? *(const us8*)(qbh + row*64 + c8) : z;
    *(us8*)((char*)Qj + (((row << 7) + c8*2) ^ ((row & 7) << 4))) = v;
  }
  if (tid < 32){ mrow[tid] = -1e30f; lrow[tid] = 0.f; }
  f32x4 o[2][4] = {};
  __syncthreads();
  for (int c0 = kbeg; c0 < kend; c0 += 128){
    // stage K chunk swizzled (clamped rows; masked later)
    #pragma unroll
    for (int it = 0; it < 4; ++it){
      int j = tid + it*256;
      int row = j >> 3, c8 = (j & 7) * 8;
      int gr = c0 + row; gr = gr < N_ ? gr : N_ - 1;
      *(us8*)((char*)Kc + (((row << 7) + c8*2) ^ ((row & 7) << 4))) =
          *(const us8*)(kbh + (long)gr*64 + c8);
    }
    { // stage V^T swizzled: 2 threads per key-column
      int row = tid >> 1, dh = (tid & 1) * 32;
      int gr = c0 + row; gr = gr < N_ ? gr : N_ - 1;
      const u16* src = vbh + (long)gr*64 + dh;
      #pragma unroll
      for (int d0 = 0; d0 < 32; d0 += 8){
        us8 vv = *(const us8*)(src + d0);
        #pragma unroll
        for (int i = 0; i < 8; i++){
          int d = dh + d0 + i;
          *(u16*)((char*)Vt + (((d << 8) + row*2) ^ ((d & 7) << 4))) = vv[i];
        }
      }
    }
    __syncthreads();
    // QK^T for this wave's 32 keys
    f32x4 sim[2][2];
    #pragma unroll
    for (int mt = 0; mt < 2; mt++){
      int arow_i = mt*16 + l15;
      bf16x8 a0 = *(const bf16x8*)((const char*)Qj + (((arow_i << 7) + quad*16)      ^ ((arow_i & 7) << 4)));
      bf16x8 a1 = *(const bf16x8*)((const char*)Qj + (((arow_i << 7) + 64 + quad*16) ^ ((arow_i & 7) << 4)));
      #pragma unroll
      for (int ntl = 0; ntl < 2; ntl++){
        int krow = wave*32 + ntl*16 + l15;
        bf16x8 b0 = *(const bf16x8*)((const char*)Kc + (((krow << 7) + quad*16)      ^ ((krow & 7) << 4)));
        bf16x8 b1 = *(const bf16x8*)((const char*)Kc + (((krow << 7) + 64 + quad*16) ^ ((krow & 7) << 4)));
        f32x4 s = {0.f, 0.f, 0.f, 0.f};
        s = __builtin_amdgcn_mfma_f32_16x16x32_bf16(a0, b0, s, 0, 0, 0);
        s = __builtin_amdgcn_mfma_f32_16x16x32_bf16(a1, b1, s, 0, 0, 0);
        if (c0 + krow >= N_){
          #pragma unroll
          for (int r = 0; r < 4; r++) s[r] = -1e30f;
        }
        sim[mt][ntl] = s;
      }
    }
    // per-row partial max (over this wave's keys)
    #pragma unroll
    for (int mt = 0; mt < 2; mt++)
    #pragma unroll
    for (int r = 0; r < 4; r++){
      float m = fmaxf(sim[mt][0][r], sim[mt][1][r]);
      #pragma unroll
      for (int sh = 1; sh < 16; sh <<= 1) m = fmaxf(m, __shfl_xor(m, sh, 64));
      if (l15 == 0) redm[wave][mt*16 + quad*4 + r] = m;
    }
    __syncthreads();
    if (tid < 32){
      float cm = fmaxf(fmaxf(redm[0][tid], redm[1][tid]), fmaxf(redm[2][tid], redm[3][tid]));
      float nm = fmaxf(mrow[tid], cm);
      arow[tid] = __expf(mrow[tid] - nm);
      mrow[tid] = nm;
    }
    __syncthreads();
    // p = exp(sim - m), write P (swizzled), partial sums, rescale O
    #pragma unroll
    for (int mt = 0; mt < 2; mt++)
    #pragma unroll
    for (int r = 0; r < 4; r++){
      int rowi = mt*16 + quad*4 + r;
      float nm = mrow[rowi];
      float p0 = __expf(sim[mt][0][r] - nm);
      float p1 = __expf(sim[mt][1][r] - nm);
      float s = p0 + p1;
      #pragma unroll
      for (int sh = 1; sh < 16; sh <<= 1) s += __shfl_xor(s, sh, 64);
      if (l15 == 0) redl[wave][rowi] = s;
      *(u16*)((char*)Pl + (((rowi << 8) + wave*64 + l15*2)      ^ ((rowi & 3) << 4))) = f2bf(p0);
      *(u16*)((char*)Pl + (((rowi << 8) + wave*64 + 32 + l15*2) ^ ((rowi & 3) << 4))) = f2bf(p1);
      float al = arow[rowi];
      #pragma unroll
      for (int ntd = 0; ntd < 4; ntd++) o[mt][ntd][r] *= al;
    }
    __syncthreads();
    if (tid < 32)
      lrow[tid] = lrow[tid]*arow[tid] + redl[0][tid] + redl[1][tid] + redl[2][tid] + redl[3][tid];
    // PV: this wave's 32 keys (swizzled Pl / Vt reads)
    #pragma unroll
    for (int mt = 0; mt < 2; mt++){
      int prow = mt*16 + l15;
      bf16x8 ap = *(const bf16x8*)((const char*)Pl + (((prow << 8) + wave*64 + quad*16) ^ ((prow & 3) << 4)));
      #pragma unroll
      for (int ntd = 0; ntd < 4; ntd++){
        int vrow = ntd*16 + l15;
        bf16x8 bv = *(const bf16x8*)((const char*)Vt + (((vrow << 8) + wave*64 + quad*16) ^ ((vrow & 7) << 4)));
        o[mt][ntd] = __builtin_amdgcn_mfma_f32_16x16x32_bf16(ap, bv, o[mt][ntd], 0, 0, 0);
      }
    }
    __syncthreads();
  }
  // merge wave partials
  #pragma unroll 1
  for (int w = 0; w < 4; ++w){
    if (wave == w){
      #pragma unroll
      for (int mt = 0; mt < 2; mt++)
      #pragma unroll
      for (int ntd = 0; ntd < 4; ntd++)
      #pragma unroll
      for (int r = 0; r < 4; r++){
        int rowi = mt*16 + quad*4 + r, d = ntd*16 + l15;
        if (w == 0) Oacc[rowi*65 + d]  = o[mt][ntd][r];
        else        Oacc[rowi*65 + d] += o[mt][ntd][r];
      }
    }
    __syncthreads();
  }
  const long pbase = (long)(bh*JSPLIT + split) * J_;
  for (int j = tid; j < J_*64; j += 256){
    int row = j >> 6, d = j & 63;
    po[(pbase + row)*64 + d] = Oacc[row*65 + d];
  }
  if (tid < J_){ pm[pbase + tid] = mrow[tid]; pl[pbase + tid] = lrow[tid]; }
}

// ---------------- attn2: fused spatial attention (bid<1024) + joint merge (bid>=1024) ----------------
// Merge path reuses spatial's Kl LDS for its small sc/lg arrays (disjoint code paths per block).
__global__ __launch_bounds__(256, 2) void attn2(const u16* __restrict__ qb, const u16* __restrict__ kb,
                                                const u16* __restrict__ vb, const float* __restrict__ sinb,
                                                const float* __restrict__ cosb, u16* __restrict__ ao,
                                                const float* __restrict__ po, const float* __restrict__ pm,
                                                const float* __restrict__ pl){
  __shared__ __attribute__((aligned(16))) u16 Kl[224*64];
  __shared__ __attribute__((aligned(16))) u16 Vt[64*256];
  __shared__ __attribute__((aligned(16))) u16 Pl[4*16*32];
  const int tid = threadIdx.x, wave = tid >> 6, lane = tid & 63, quad = lane >> 4, l15 = lane & 15;
  if (blockIdx.x >= 1024){
    // ---- joint merge path ----
    const int bh = blockIdx.x - 1024;
    float* sc = (float*)Kl;                 // [JSPLIT][J_]
    float* lg = sc + JSPLIT*J_;             // [J_]
    if (tid < J_){
      float m = -1e30f;
      #pragma unroll
      for (int s = 0; s < JSPLIT; s++) m = fmaxf(m, pm[(bh*JSPLIT + s)*J_ + tid]);
      float l = 0.f;
      #pragma unroll
      for (int s = 0; s < JSPLIT; s++){
        float e = __expf(pm[(bh*JSPLIT + s)*J_ + tid] - m);
        sc[s*J_ + tid] = e;
        l += pl[(bh*JSPLIT + s)*J_ + tid] * e;
      }
      lg[tid] = l;
    }
    __syncthreads();
    const int b = bh >> 3, h = bh & 7;
    for (int j = tid; j < J_*64; j += 256){
      int row = j >> 6, d = j & 63;
      float acc = 0.f;
      #pragma unroll
      for (int s = 0; s < JSPLIT; s++)
        acc += po[((long)(bh*JSPLIT + s)*J_ + row)*64 + d] * sc[s*J_ + row];
      ao[((long)(b*N_ + row))*512 + h*64 + d] = f2bf(acc / lg[row]);
    }
    return;
  }
  // ---- spatial attention path ----
  const int bh = blockIdx.x >> 4, f = blockIdx.x & 15;
  const u16* kbh = kb + (long)bh * N_ * 64;
  const u16* vbh = vb + (long)bh * N_ * 64;
  const u16* qbh = qb + (long)bh * N_ * 64 + (long)(J_ + f*NS_) * 64;
  // stage K rows 0..223, swizzled (rows 24..219 get RoPE on dims<32; rows 220..223 zeroed)
  for (int j = tid; j < 224*8; j += 256){
    int n = j >> 3, c8 = (j & 7) * 8;
    us8 kv;
    if (n < SKEY){
      kv = *(const us8*)(kbh + (long)((n < J_) ? n : n + f*NS_) * 64 + c8);
      if (n >= J_ && c8 < 32){
        int ns = n - J_;
        kv = rope8(kv, sinb + ns*32 + c8, cosb + ns*32 + c8);
      }
    } else {
      #pragma unroll
      for (int i = 0; i < 8; i++) kv[i] = 0;
    }
    *(us8*)((char*)Kl + (((n << 7) + c8*2) ^ ((n & 7) << 4))) = kv;
  }
  // stage V^T swizzled: thread t owns key-column n = t
  if (tid < 224){
    const int n = tid;
    const bool valid = n < SKEY;
    const u16* src = vbh + (long)((n < J_) ? n : n + f*NS_) * 64;
    #pragma unroll
    for (int d0 = 0; d0 < 64; d0 += 8){
      us8 vv;
      if (valid) vv = *(const us8*)(src + d0);
      else {
        #pragma unroll
        for (int i = 0; i < 8; i++) vv[i] = 0;
      }
      #pragma unroll
      for (int i = 0; i < 8; i++){
        int d = d0 + i;
        *(u16*)((char*)Vt + (((d << 9) + n*2) ^ ((d & 7) << 4))) = vv[i];
      }
    }
  }
  __syncthreads();
  const int b = bh >> 3, h = bh & 7;
  #pragma unroll 1
  for (int mt = 0; mt < 4; ++mt){
    int qrow = wave*64 + mt*16 + l15;
    int qi = qrow < NS_ ? qrow : NS_ - 1;           // clamp padded rows (stores guarded)
    U8 a0u, a1u;
    a0u.u = *(const us8*)(qbh + (long)qi*64 + quad*8);
    a0u.u = rope8(a0u.u, sinb + qi*32 + quad*8, cosb + qi*32 + quad*8);
    a1u.u = *(const us8*)(qbh + (long)qi*64 + 32 + quad*8);
    f32x4 sim[14];
    #pragma unroll
    for (int nt = 0; nt < 14; ++nt){
      int krow = nt*16 + l15;
      bf16x8 b0 = *(const bf16x8*)((const char*)Kl + (((krow << 7) + quad*16)      ^ ((krow & 7) << 4)));
      bf16x8 b1 = *(const bf16x8*)((const char*)Kl + (((krow << 7) + 64 + quad*16) ^ ((krow & 7) << 4)));
      f32x4 s = {0.f, 0.f, 0.f, 0.f};
      s = __builtin_amdgcn_mfma_f32_16x16x32_bf16(a0u.b, b0, s, 0, 0, 0);
      s = __builtin_amdgcn_mfma_f32_16x16x32_bf16(a1u.b, b1, s, 0, 0, 0);
      sim[nt] = s;
    }
    if (l15 >= 12){  // keys 220..223 are padding
      #pragma unroll
      for (int r = 0; r < 4; r++) sim[13][r] = -1e30f;
    }
    // full softmax in registers (rows live in quads; reduce over 16 lanes)
    #pragma unroll
    for (int r = 0; r < 4; r++){
      float m = sim[0][r];
      #pragma unroll
      for (int nt = 1; nt < 14; nt++) m = fmaxf(m, sim[nt][r]);
      #pragma unroll
      for (int sh = 1; sh < 16; sh <<= 1) m = fmaxf(m, __shfl_xor(m, sh, 64));
      float s = 0.f;
      #pragma unroll
      for (int nt = 0; nt < 14; nt++){ float p = __expf(sim[nt][r] - m); sim[nt][r] = p; s += p; }
      #pragma unroll
      for (int sh = 1; sh < 16; sh <<= 1) s += __shfl_xor(s, sh, 64);
      float inv = 1.f / s;
      #pragma unroll
      for (int nt = 0; nt < 14; nt++) sim[nt][r] *= inv;
    }
    // PV in 7 chunks of 32 keys; P round-trip through per-wave LDS (no block barrier needed).
    f32x4 o[4] = {};
    u16* pw = Pl + wave*512;
    #pragma unroll
    for (int c = 0; c < 7; c++){
      #pragma unroll
      for (int h2 = 0; h2 < 2; h2++){
        #pragma unroll
        for (int r = 0; r < 4; r++)
          pw[(quad*4 + r)*32 + h2*16 + l15] = f2bf(sim[2*c + h2][r]);
      }
      __builtin_amdgcn_wave_barrier();
      bf16x8 ap = *(const bf16x8*)(pw + l15*32 + quad*8);
      #pragma unroll
      for (int ntd = 0; ntd < 4; ntd++){
        int vrow = ntd*16 + l15;
        bf16x8 bv = *(const bf16x8*)((const char*)Vt + (((vrow << 9) + c*64 + quad*16) ^ ((vrow & 7) << 4)));
        o[ntd] = __builtin_amdgcn_mfma_f32_16x16x32_bf16(ap, bv, o[ntd], 0, 0, 0);
      }
      __builtin_amdgcn_wave_barrier();
    }
    #pragma unroll
    for (int ntd = 0; ntd < 4; ntd++)
    #pragma unroll
    for (int r = 0; r < 4; r++){
      int qr = wave*64 + mt*16 + quad*4 + r;
      if (qr < NS_){
        int n = J_ + f*NS_ + qr;
        ao[((long)(b*N_ + n))*512 + h*64 + ntd*16 + l15] = f2bf(o[ntd][r]);
      }
    }
  }
}

extern "C" void kernel_launch(void* const* d_in, const int* in_sizes, int n_in,
                              void* d_out, int out_size, void* d_ws, size_t ws_size,
                              hipStream_t stream){
  (void)in_sizes; (void)n_in; (void)out_size; (void)ws_size;
  const float* x    = (const float*)d_in[0];
  const float* wqkv = (const float*)d_in[1];
  const float* wout = (const float*)d_in[2];
  const float* bout = (const float*)d_in[3];
  const float* sinb = (const float*)d_in[4];
  const float* cosb = (const float*)d_in[5];
  float* out = (float*)d_out;
  u16* ws  = (u16*)d_ws;
  u16* qb  = ws;                       // [64][3160][64] bf16
  u16* kb  = qb  + 12943360;
  u16* vb  = kb  + 12943360;
  u16* xb  = vb  + 12943360;           // x bf16 [25280][512]; later reused as aob [B][N][512]
  u16* aob = xb;                       //   (alias: xb dead after gemm_qkv)
  u16* wt1 = xb  + 12943360;           // w_qkv^T bf16 [1536][512]
  u16* wt2 = wt1 + 786432;             // w_out^T bf16 [512][512]
  float* po = (float*)(wt2 + 262144);  // [64][JSPLIT][24][64] fp32 partial O
  float* pm = po + 64*JSPLIT*J_*64;    // [64][JSPLIT][24]
  float* pl = pm + 64*JSPLIT*J_;
  prep<<<dim3(13664), 256, 0, stream>>>(x, xb, 12943360/4, wqkv, wt1, wout, wt2);
  gemm_qkv<<<dim3(2376), 256, 0, stream>>>(xb, wt1, qb, kb, vb);
  joint_part<<<dim3(64, JSPLIT), 256, 0, stream>>>(qb, kb, vb, po, pm, pl);
  attn2<<<dim3(1088), 256, 0, stream>>>(qb, kb, vb, sinb, cosb, aob, po, pm, pl);
  gemm_out<<<dim3(792), 256, 0, stream>>>(aob, wt2, bout, out);
}